// Round 2
// baseline (268.738 us; speedup 1.0000x reference)
//
#include <hip/hip_runtime.h>

// PhysicsPriorGenerator, two-phase:
//   A: per-column (prior,b,a): dt = d/cos((th+ang)*pi/180), inv = valid ? 1/sum_j exp2(K*diff^2) : 0
//   B: out[pb][j][a] = exp2(K*(dep_j - dt)^2) * inv   (268 MB fp32, write-bound ~43 us roofline)
// K = -2/(2*sigma^2) * log2(e) = -2.8853900817779268  (sigma = 0.5)

#define DD 512
#define AA 256
#define K2 (-2.8853900817779268f)
#define DSTEP (50.0f / 511.0f)
#define ASTEP (60.0f / 255.0f)

// ---- Kernel A: one thread per column; ws[col] = {dt, inv} (float2) ----
__global__ __launch_bounds__(256) void prior_setup(const float* __restrict__ p0,
                                                   const float* __restrict__ p1,
                                                   float2* __restrict__ ws) {
    const int col = blockIdx.x * 256 + threadIdx.x;   // 0 .. 2*256*256-1
    const int pb  = col >> 8;                          // prior*256 + b
    const int a   = col & 255;
    const float* __restrict__ pp = (pb < 256) ? (p0 + 3 * pb) : (p1 + 3 * (pb - 256));
    const float d  = pp[1];
    const float th = pp[2];

    const float ang = -30.0f + (float)a * ASTEP;
    const float rad = (th + ang) * 0.017453292519943295f;
    const float dt  = d / cosf(rad);
    const bool valid = (dt > 0.0f) && (dt < 50.0f);

    float s0 = 0.0f, s1 = 0.0f, s2 = 0.0f, s3 = 0.0f;
    #pragma unroll 4
    for (int j = 0; j < DD; j += 4) {
        float x0 = (float)(j + 0) * DSTEP - dt;
        float x1 = (float)(j + 1) * DSTEP - dt;
        float x2 = (float)(j + 2) * DSTEP - dt;
        float x3 = (float)(j + 3) * DSTEP - dt;
        s0 += __builtin_amdgcn_exp2f(K2 * x0 * x0);
        s1 += __builtin_amdgcn_exp2f(K2 * x1 * x1);
        s2 += __builtin_amdgcn_exp2f(K2 * x2 * x2);
        s3 += __builtin_amdgcn_exp2f(K2 * x3 * x3);
    }
    const float sum = (s0 + s1) + (s2 + s3);
    const float den = (sum > 0.0f) ? sum : 1.0f;
    float2 r;
    r.x = valid ? dt : 1.0e9f;          // clamped dt keeps kernel-B exp finite (-> 0)
    r.y = valid ? (1.0f / den) : 0.0f;
    ws[col] = r;
}

// ---- Kernel B: pure write stream. Block = (pb, chunk); 64 rows x 256 angles per block ----
__global__ __launch_bounds__(256) void prior_write(const float4* __restrict__ ws,
                                                   float* __restrict__ out) {
    const int gid   = blockIdx.x;
    const int pb    = gid >> 3;       // 0..511
    const int chunk = gid & 7;        // 0..7 -> rows [chunk*64, +64)
    const int t     = threadIdx.x;
    const int a4    = (t & 63) * 4;   // angle group (wave-contiguous -> 1KB coalesced stores)
    const int jb    = t >> 6;         // 4 sub-chunks of 16 rows

    // ws as float4: {dt[2k], inv[2k], dt[2k+1], inv[2k+1]}
    const float4 e0 = ws[pb * 128 + (t & 63) * 2];
    const float4 e1 = ws[pb * 128 + (t & 63) * 2 + 1];

    float* __restrict__ outp = out + (size_t)pb * (DD * AA) + a4;
    const int j0 = chunk * 64 + jb * 16;
    #pragma unroll
    for (int i = 0; i < 16; ++i) {
        const int j = j0 + i;
        const float dep = (float)j * DSTEP;
        float4 v;
        float dx = dep - e0.x; v.x = __builtin_amdgcn_exp2f(K2 * dx * dx) * e0.y;
        float dy = dep - e0.z; v.y = __builtin_amdgcn_exp2f(K2 * dy * dy) * e0.w;
        float dz = dep - e1.x; v.z = __builtin_amdgcn_exp2f(K2 * dz * dz) * e1.y;
        float dw = dep - e1.z; v.w = __builtin_amdgcn_exp2f(K2 * dw * dw) * e1.w;
        *(float4*)(outp + (size_t)j * AA) = v;
    }
}

extern "C" void kernel_launch(void* const* d_in, const int* in_sizes, int n_in,
                              void* d_out, int out_size, void* d_ws, size_t ws_size,
                              hipStream_t stream) {
    const float* p0 = (const float*)d_in[0];   // p        (256 x 3)
    const float* p1 = (const float*)d_in[1];   // p_calib  (256 x 3)
    float* out = (float*)d_out;                // 2 x 256 x 512 x 256 fp32
    float2* ws = (float2*)d_ws;                // 131072 x {dt, inv} = 1 MB

    prior_setup<<<dim3(512), dim3(256), 0, stream>>>(p0, p1, ws);
    prior_write<<<dim3(512 * 8), dim3(256), 0, stream>>>((const float4*)ws, out);
}